// Round 5
// baseline (60317.749 us; speedup 1.0000x reference)
//
#include <hip/hip_runtime.h>
#include <math.h>

#define T_STEPS 8192
#define I_DIM   64
#define H_DIM   2048
#define O_DIM   128
#define NBLK    256     // one block per CU; each CU owns 8 h-indices
#define NTHR    512     // 8 waves; wave w owns h-index cu*8+w (all 4 gate rows)
#define NSLOT   4       // h slot ring depth (reset 2 ahead)
#define NAN_BITS 0x7FC00000u

typedef unsigned int v4u __attribute__((ext_vector_type(4)));
typedef float        v4f __attribute__((ext_vector_type(4)));

__device__ __forceinline__ float sigmoid_f(float x) {
    return 1.0f / (1.0f + __expf(-x));
}
__device__ __forceinline__ float tanh_fast(float x) {
    // 2*sigmoid(2x)-1; saturates correctly for |x| large
    return 2.0f / (1.0f + __expf(-2.0f * x)) - 1.0f;
}

__global__ void init_ws_kernel(unsigned int* Hbits) {
    int tid = blockIdx.x * blockDim.x + threadIdx.x;
    if (tid < NSLOT * H_DIM) {
        // slot 0 = h_0 = 0.0f; slots 1..3 = NaN sentinel ("not ready")
        Hbits[tid] = (tid < H_DIM) ? 0u : NAN_BITS;
    }
}

// Persistent LSTM. One block/CU, 8 waves. Wave w owns h-index hidx=cu*8+w and
// its 4 gate rows g*2048+hidx. Data-as-flag (NaN sentinel) h ring in LLC via
// AGENT-scope relaxed atomics (sc1 -> LLC-served; NEVER system scope: sc0+sc1
// bypasses LLC to HBM and cost 2x in round 4). Single barrier per step via
// double-buffered LDS h.
// k-mapping: lane l covers k = 256*m + 4*l + j (m=0..7, j=0..3) -> ds_read_b128.
__global__ __launch_bounds__(NTHR, 2) void lstm_persistent(
    const float* __restrict__ x,     // [T, 64]
    const float* __restrict__ Wih,   // [8192, 64]
    const float* __restrict__ Whh,   // [8192, 2048]
    const float* __restrict__ bih,   // [8192]
    const float* __restrict__ bhh,   // [8192]
    unsigned int* __restrict__ Hbits)// [NSLOT][2048] in ws (float bits)
{
    const int cu   = blockIdx.x;
    const int tid  = threadIdx.x;
    const int w    = tid >> 6;
    const int lane = tid & 63;
    const int hidx = cu * 8 + w;     // owned h index

    __shared__ float hbuf[2][H_DIM];   // 16 KB double buffer

    // ---- one-time: W_hh rows for the 4 gates of hidx into registers ----
    float wreg[4][8][4];
#pragma unroll
    for (int g = 0; g < 4; g++) {
        const float* rp = Whh + (size_t)(g * H_DIM + hidx) * H_DIM;
#pragma unroll
        for (int m = 0; m < 8; m++) {
            v4f wv = *(const v4f*)(rp + m * 256 + lane * 4);  // coalesced 16B
            wreg[g][m][0] = wv[0]; wreg[g][m][1] = wv[1];
            wreg[g][m][2] = wv[2]; wreg[g][m][3] = wv[3];
        }
    }
    // W_ih: lane l holds column l of the 4 gate rows
    float xwih[4];
#pragma unroll
    for (int g = 0; g < 4; g++)
        xwih[g] = Wih[(size_t)(g * H_DIM + hidx) * I_DIM + lane];
    // biases (used by lane 0 only)
    float bias[4];
#pragma unroll
    for (int g = 0; g < 4; g++)
        bias[g] = bih[g * H_DIM + hidx] + bhh[g * H_DIM + hidx];

    float cstate = 0.0f;   // live in lane 0 of each wave

    for (int t = 0; t < T_STEPS; t++) {
        const int sr = t & (NSLOT - 1);
        const int sw = (t + 1) & (NSLOT - 1);
        const int sz = (t + 2) & (NSLOT - 1);
        const int pb = t & 1;

        float xv = x[(size_t)t * I_DIM + lane];   // issue before the spin

        // ---- 1. spin on own 4 dwords of h_t (data-as-flag), stage to LDS ----
        // AGENT-scope relaxed atomics: LLC-served, proven instruction (round 3).
        {
            const unsigned int* Hr = Hbits + sr * H_DIM + tid * 4;
            unsigned int u0, u1, u2, u3;
            do {
                u0 = __hip_atomic_load(Hr + 0, __ATOMIC_RELAXED, __HIP_MEMORY_SCOPE_AGENT);
                u1 = __hip_atomic_load(Hr + 1, __ATOMIC_RELAXED, __HIP_MEMORY_SCOPE_AGENT);
                u2 = __hip_atomic_load(Hr + 2, __ATOMIC_RELAXED, __HIP_MEMORY_SCOPE_AGENT);
                u3 = __hip_atomic_load(Hr + 3, __ATOMIC_RELAXED, __HIP_MEMORY_SCOPE_AGENT);
            } while ((u0 == NAN_BITS) | (u1 == NAN_BITS) |
                     (u2 == NAN_BITS) | (u3 == NAN_BITS));
            v4u u; u[0] = u0; u[1] = u1; u[2] = u2; u[3] = u3;
            *(v4u*)&hbuf[pb][tid * 4] = u;
        }
        // reset own dword 2 slots ahead (holds fully-consumed h_{t-2}); same
        // thread republishes this exact address at step t+1 -> same-addr order.
        if (lane == 0) {
            __hip_atomic_store(Hbits + sz * H_DIM + hidx, NAN_BITS,
                               __ATOMIC_RELAXED, __HIP_MEMORY_SCOPE_AGENT);
        }
        __syncthreads();   // the ONLY barrier per step

        // ---- 2. dot products: 4 gate rows, 8 x (b128 LDS + 16 FMA) ----
        float a0 = 0.f, a1 = 0.f, a2 = 0.f, a3 = 0.f;
#pragma unroll
        for (int m = 0; m < 8; m++) {
            v4f hv = *(const v4f*)&hbuf[pb][m * 256 + lane * 4];
            a0 += wreg[0][m][0] * hv[0] + wreg[0][m][1] * hv[1]
                + wreg[0][m][2] * hv[2] + wreg[0][m][3] * hv[3];
            a1 += wreg[1][m][0] * hv[0] + wreg[1][m][1] * hv[1]
                + wreg[1][m][2] * hv[2] + wreg[1][m][3] * hv[3];
            a2 += wreg[2][m][0] * hv[0] + wreg[2][m][1] * hv[1]
                + wreg[2][m][2] * hv[2] + wreg[2][m][3] * hv[3];
            a3 += wreg[3][m][0] * hv[0] + wreg[3][m][1] * hv[1]
                + wreg[3][m][2] * hv[2] + wreg[3][m][3] * hv[3];
        }
        // fold in W_ih * x_t (lane l holds column l)
        a0 += xwih[0] * xv;
        a1 += xwih[1] * xv;
        a2 += xwih[2] * xv;
        a3 += xwih[3] * xv;

        // ---- 3. butterfly reduce to lane 0 ----
#pragma unroll
        for (int off = 32; off; off >>= 1) {
            a0 += __shfl_xor(a0, off, 64);
            a1 += __shfl_xor(a1, off, 64);
            a2 += __shfl_xor(a2, off, 64);
            a3 += __shfl_xor(a3, off, 64);
        }

        // ---- 4. elementwise + publish (lane 0 of this wave; no 2nd barrier) ----
        if (lane == 0) {
            float iv = sigmoid_f(a0 + bias[0]);
            float fv = sigmoid_f(a1 + bias[1]);
            float gv = tanh_fast(a2 + bias[2]);
            float ov = sigmoid_f(a3 + bias[3]);
            cstate = fv * cstate + iv * gv;
            float hval = ov * tanh_fast(cstate);
            __hip_atomic_store(Hbits + sw * H_DIM + hidx, __float_as_uint(hval),
                               __ATOMIC_RELAXED, __HIP_MEMORY_SCOPE_AGENT);
        }
        // next-step staging targets the other LDS buffer; barrier of step t+1
        // protects buffer reuse at t+2.
    }
}

// Final linear: out[o] = h_T . W_lin[o,:] + b_lin[o].  One wave per output.
// h_T lives in slot (T & 3) == 0.
__global__ void final_linear(const float* __restrict__ hT,
                             const float* __restrict__ Wlin,
                             const float* __restrict__ blin,
                             float* __restrict__ out)
{
    int gw   = (blockIdx.x * blockDim.x + threadIdx.x) >> 6;
    int lane = threadIdx.x & 63;
    if (gw < O_DIM) {
        const float* wp = Wlin + (size_t)gw * H_DIM;
        float s = 0.f;
        for (int k = lane; k < H_DIM; k += 64)
            s += wp[k] * hT[k];
#pragma unroll
        for (int off = 32; off; off >>= 1) s += __shfl_xor(s, off, 64);
        if (lane == 0) out[gw] = s + blin[gw];
    }
}

extern "C" void kernel_launch(void* const* d_in, const int* in_sizes, int n_in,
                              void* d_out, int out_size, void* d_ws, size_t ws_size,
                              hipStream_t stream)
{
    const float* x    = (const float*)d_in[0];
    const float* Wih  = (const float*)d_in[1];
    const float* Whh  = (const float*)d_in[2];
    const float* bih  = (const float*)d_in[3];
    const float* bhh  = (const float*)d_in[4];
    const float* Wlin = (const float*)d_in[5];
    const float* blin = (const float*)d_in[6];
    float* out = (float*)d_out;

    unsigned int* Hbits = (unsigned int*)d_ws;

    hipLaunchKernelGGL(init_ws_kernel, dim3((NSLOT * H_DIM + 255) / 256), dim3(256),
                       0, stream, Hbits);

    void* args[] = { (void*)&x, (void*)&Wih, (void*)&Whh, (void*)&bih, (void*)&bhh,
                     (void*)&Hbits };
    hipLaunchCooperativeKernel(reinterpret_cast<void*>(lstm_persistent),
                               dim3(NBLK), dim3(NTHR), args, 0, stream);

    // h_T is in slot (T_STEPS & 3) == 0
    hipLaunchKernelGGL(final_linear, dim3(32), dim3(256), 0, stream,
                       (const float*)Hbits, Wlin, blin, out);
}

// Round 6
// 22534.845 us; speedup vs baseline: 2.6766x; 2.6766x over previous
//
#include <hip/hip_runtime.h>
#include <math.h>

#define T_STEPS 8192
#define I_DIM   64
#define H_DIM   2048
#define O_DIM   128
#define NBLK    256     // one block per CU; each owns 8 h-indices (32 gate rows)
#define NTHR    512     // 8 waves
#define NSLOT   4       // h slot ring depth
#define NAN_BITS 0x7FC00000u

// ws layout: float Hbuf[NSLOT][2048]
__device__ __forceinline__ float sigmoid_f(float x) {
    return 1.0f / (1.0f + __expf(-x));
}
__device__ __forceinline__ float tanh_fast(float x) {
    // 2*sigmoid(2x)-1; saturates correctly for |x| large
    return 2.0f / (1.0f + __expf(-2.0f * x)) - 1.0f;
}

__global__ void init_ws_kernel(unsigned int* Hbits) {
    int tid = blockIdx.x * blockDim.x + threadIdx.x;
    if (tid < NSLOT * H_DIM) {
        // slot 0 = h_0 = 0.0f; slots 1..3 = NaN sentinel ("not ready")
        Hbits[tid] = (tid < H_DIM) ? 0u : NAN_BITS;
    }
}

// Persistent LSTM recurrence — round-3 structure (proven 3.03 us/step).
// One block per CU. Data-as-flag (NaN sentinel) h ring in LLC, agent-scope
// relaxed atomics only (no fences, no flags). Publish/reset are ONE coalesced
// 8-lane store from wave 0 (WRITE_SIZE signature 131 MB — do not scatter;
// scattering was the round-4/5 8x-write regression).
// Wave w: gate q = w>>1, joff = (w&1)*4; rows = q*2048 + cu*8 + joff + i
// Lane covers k = kk*64 + lane (conflict-free LDS, coalesced weight loads)
__global__ __launch_bounds__(NTHR, 2) void lstm_persistent(
    const float* __restrict__ x,     // [T, 64]
    const float* __restrict__ Wih,   // [8192, 64]
    const float* __restrict__ Whh,   // [8192, 2048]
    const float* __restrict__ bih,   // [8192]
    const float* __restrict__ bhh,   // [8192]
    unsigned int* __restrict__ Hbits)// [NSLOT][2048] in ws (float bits)
{
    const int cu   = blockIdx.x;
    const int tid  = threadIdx.x;
    const int w    = tid >> 6;
    const int lane = tid & 63;

    __shared__ float hbuf[H_DIM];   // 8 KB
    __shared__ float xbuf[I_DIM];
    __shared__ float gbuf[32];      // gbuf[g*8 + j] = pre-activation of gate g, h-sub j

    const int q    = w >> 1;
    const int joff = (w & 1) * 4;
    const int row0 = q * H_DIM + cu * 8 + joff;

    // ---- one-time: W_hh fragment into registers ----
    float wreg[4][32];
#pragma unroll
    for (int i = 0; i < 4; i++) {
        const float* p = Whh + (size_t)(row0 + i) * H_DIM + lane;
#pragma unroll
        for (int kk = 0; kk < 32; kk++)
            wreg[i][kk] = p[kk * 64];
    }
    // x-part: lane handles row (row0 + (lane>>4)), k-range (lane&15)*4 .. +4
    float xw[4];
    {
        const int xr = row0 + (lane >> 4);
        const float* p = Wih + (size_t)xr * I_DIM + (lane & 15) * 4;
#pragma unroll
        for (int m = 0; m < 4; m++) xw[m] = p[m];
    }
    // biases: every wave keeps them (elementwise phase is replicated per wave)
    float bias[4] = {0.f, 0.f, 0.f, 0.f};
    if (lane < 8) {
#pragma unroll
        for (int g = 0; g < 4; g++) {
            int r = g * H_DIM + cu * 8 + lane;
            bias[g] = bih[r] + bhh[r];
        }
    }
    float cstate = 0.0f;   // replicated in lanes 0..7 of every wave

    for (int t = 0; t < T_STEPS; t++) {
        const int slot_r = t & (NSLOT - 1);
        const int slot_w = (t + 1) & (NSLOT - 1);
        const int slot_z = (t + 2) & (NSLOT - 1);

        // ---- 1. poll h_t (data-as-flag) and stage into LDS ----
        // s_sleep(2) backoff on failed passes: cuts LLC poll-request pressure
        // (~65K line-req/pass chip-wide) at <=128cy detect cost.
        {
            const unsigned int* Hr = Hbits + slot_r * H_DIM;
            unsigned int u0, u1, u2, u3;
            for (;;) {
                u0 = __hip_atomic_load(Hr + tid,             __ATOMIC_RELAXED, __HIP_MEMORY_SCOPE_AGENT);
                u1 = __hip_atomic_load(Hr + tid + 1 * NTHR,  __ATOMIC_RELAXED, __HIP_MEMORY_SCOPE_AGENT);
                u2 = __hip_atomic_load(Hr + tid + 2 * NTHR,  __ATOMIC_RELAXED, __HIP_MEMORY_SCOPE_AGENT);
                u3 = __hip_atomic_load(Hr + tid + 3 * NTHR,  __ATOMIC_RELAXED, __HIP_MEMORY_SCOPE_AGENT);
                bool miss = (u0 == NAN_BITS) | (u1 == NAN_BITS) |
                            (u2 == NAN_BITS) | (u3 == NAN_BITS);
                if (!miss) break;
                __builtin_amdgcn_s_sleep(2);
            }
            hbuf[tid]            = __uint_as_float(u0);
            hbuf[tid + 1 * NTHR] = __uint_as_float(u1);
            hbuf[tid + 2 * NTHR] = __uint_as_float(u2);
            hbuf[tid + 3 * NTHR] = __uint_as_float(u3);
            if (tid < I_DIM) xbuf[tid] = x[(size_t)t * I_DIM + tid];
        }
        // reset own chunk 2 slots ahead (holds h_{t-2}, fully consumed, skew<=1).
        // Coalesced: 8 lanes of wave 0, one 32B transaction.
        if (w == 0 && lane < 8) {
            __hip_atomic_store(Hbits + slot_z * H_DIM + cu * 8 + lane, NAN_BITS,
                               __ATOMIC_RELAXED, __HIP_MEMORY_SCOPE_AGENT);
        }
        __syncthreads();

        // ---- 2. dot products: 4 rows per wave ----
        float acc0 = 0.f, acc1 = 0.f, acc2 = 0.f, acc3 = 0.f;
#pragma unroll
        for (int kk = 0; kk < 32; kk++) {
            float hv = hbuf[kk * 64 + lane];
            acc0 += wreg[0][kk] * hv;
            acc1 += wreg[1][kk] * hv;
            acc2 += wreg[2][kk] * hv;
            acc3 += wreg[3][kk] * hv;
        }
        {   // fold in W_ih * x_t
            float xp = 0.f;
            const int b = (lane & 15) * 4;
#pragma unroll
            for (int m = 0; m < 4; m++) xp += xw[m] * xbuf[b + m];
            const int sel = lane >> 4;
            acc0 += (sel == 0) ? xp : 0.0f;
            acc1 += (sel == 1) ? xp : 0.0f;
            acc2 += (sel == 2) ? xp : 0.0f;
            acc3 += (sel == 3) ? xp : 0.0f;
        }
#pragma unroll
        for (int off = 32; off; off >>= 1) {
            acc0 += __shfl_xor(acc0, off, 64);
            acc1 += __shfl_xor(acc1, off, 64);
            acc2 += __shfl_xor(acc2, off, 64);
            acc3 += __shfl_xor(acc3, off, 64);
        }
        if (lane == 0) {
            gbuf[q * 8 + joff + 0] = acc0;
            gbuf[q * 8 + joff + 1] = acc1;
            gbuf[q * 8 + joff + 2] = acc2;
            gbuf[q * 8 + joff + 3] = acc3;
        }
        __syncthreads();

        // ---- 3. elementwise cell update, replicated in every wave (lanes 0..7);
        //         wave 0 publishes — ONE coalesced 32B store = the ready flag ----
        if (lane < 8) {
            float gi = gbuf[0 * 8 + lane] + bias[0];
            float gf = gbuf[1 * 8 + lane] + bias[1];
            float gg = gbuf[2 * 8 + lane] + bias[2];
            float go = gbuf[3 * 8 + lane] + bias[3];
            float iv = sigmoid_f(gi);
            float fv = sigmoid_f(gf);
            float gv = tanh_fast(gg);
            float ov = sigmoid_f(go);
            cstate = fv * cstate + iv * gv;
            float hval = ov * tanh_fast(cstate);
            if (w == 0) {
                __hip_atomic_store(Hbits + slot_w * H_DIM + cu * 8 + lane,
                                   __float_as_uint(hval),
                                   __ATOMIC_RELAXED, __HIP_MEMORY_SCOPE_AGENT);
            }
        }
        // next iteration's poll phase touches only Hbits/hbuf/xbuf; gbuf reuse
        // is protected by the next iteration's first __syncthreads.
    }
}

// Final linear: out[o] = h_T . W_lin[o,:] + b_lin[o].  One wave per output.
// h_T lives in slot (T & 3) == 0.
__global__ void final_linear(const float* __restrict__ hT,
                             const float* __restrict__ Wlin,
                             const float* __restrict__ blin,
                             float* __restrict__ out)
{
    int gw   = (blockIdx.x * blockDim.x + threadIdx.x) >> 6;
    int lane = threadIdx.x & 63;
    if (gw < O_DIM) {
        const float* wp = Wlin + (size_t)gw * H_DIM;
        float s = 0.f;
        for (int k = lane; k < H_DIM; k += 64)
            s += wp[k] * hT[k];
#pragma unroll
        for (int off = 32; off; off >>= 1) s += __shfl_xor(s, off, 64);
        if (lane == 0) out[gw] = s + blin[gw];
    }
}

extern "C" void kernel_launch(void* const* d_in, const int* in_sizes, int n_in,
                              void* d_out, int out_size, void* d_ws, size_t ws_size,
                              hipStream_t stream)
{
    const float* x    = (const float*)d_in[0];
    const float* Wih  = (const float*)d_in[1];
    const float* Whh  = (const float*)d_in[2];
    const float* bih  = (const float*)d_in[3];
    const float* bhh  = (const float*)d_in[4];
    const float* Wlin = (const float*)d_in[5];
    const float* blin = (const float*)d_in[6];
    float* out = (float*)d_out;

    unsigned int* Hbits = (unsigned int*)d_ws;

    hipLaunchKernelGGL(init_ws_kernel, dim3((NSLOT * H_DIM + 255) / 256), dim3(256),
                       0, stream, Hbits);

    void* args[] = { (void*)&x, (void*)&Wih, (void*)&Whh, (void*)&bih, (void*)&bhh,
                     (void*)&Hbits };
    hipLaunchCooperativeKernel(reinterpret_cast<void*>(lstm_persistent),
                               dim3(NBLK), dim3(NTHR), args, 0, stream);

    // h_T is in slot (T_STEPS & 3) == 0
    hipLaunchKernelGGL(final_linear, dim3(32), dim3(256), 0, stream,
                       (const float*)Hbits, Wlin, blin, out);
}

// Round 7
// 21121.263 us; speedup vs baseline: 2.8558x; 1.0669x over previous
//
#include <hip/hip_runtime.h>
#include <math.h>

#define T_STEPS 8192
#define I_DIM   64
#define H_DIM   2048
#define O_DIM   128
#define NBLK    256     // one block per CU; each owns 8 h-indices (32 gate rows)
#define NTHR    512     // 8 waves
#define NSLOT   4       // h slot ring depth
#define NAN_BITS 0x7FC00000u

typedef float v4f __attribute__((ext_vector_type(4)));

// ws layout: float Hbuf[NSLOT][2048]
__device__ __forceinline__ float sigmoid_f(float x) {
    return 1.0f / (1.0f + __expf(-x));
}
__device__ __forceinline__ float tanh_fast(float x) {
    // 2*sigmoid(2x)-1; saturates correctly for |x| large
    return 2.0f / (1.0f + __expf(-2.0f * x)) - 1.0f;
}

__global__ void init_ws_kernel(unsigned int* Hbits) {
    int tid = blockIdx.x * blockDim.x + threadIdx.x;
    if (tid < NSLOT * H_DIM) {
        // slot 0 = h_0 = 0.0f; slots 1..3 = NaN sentinel ("not ready")
        Hbits[tid] = (tid < H_DIM) ? 0u : NAN_BITS;
    }
}

// Persistent LSTM recurrence — round-6 fabric (proven 2.75 us/step) + b128 LDS
// dot + packed-f32 FMA. One block per CU. Data-as-flag (NaN sentinel) h ring in
// LLC, agent-scope relaxed atomics only. Publish/reset are ONE coalesced 8-lane
// store from wave 0 (WRITE_SIZE signature 131 MB — do not scatter; scattering
// was the round-4/5 8x-write regression).
// Wave w: gate q = w>>1, joff = (w&1)*4; rows = q*2048 + cu*8 + joff + i
// Dot k-mapping: lane l covers k = m*256 + l*4 + j (m=0..7, j=0..3) ->
// one ds_read_b128 per m, h reused across the wave's 4 rows.
__global__ __launch_bounds__(NTHR, 2) void lstm_persistent(
    const float* __restrict__ x,     // [T, 64]
    const float* __restrict__ Wih,   // [8192, 64]
    const float* __restrict__ Whh,   // [8192, 2048]
    const float* __restrict__ bih,   // [8192]
    const float* __restrict__ bhh,   // [8192]
    unsigned int* __restrict__ Hbits)// [NSLOT][2048] in ws (float bits)
{
    const int cu   = blockIdx.x;
    const int tid  = threadIdx.x;
    const int w    = tid >> 6;
    const int lane = tid & 63;

    __shared__ float hbuf[H_DIM];   // 8 KB, layout hbuf[k] = h[k]
    __shared__ float xbuf[I_DIM];
    __shared__ float gbuf[32];      // gbuf[g*8 + j] = pre-activation of gate g, h-sub j

    const int q    = w >> 1;
    const int joff = (w & 1) * 4;
    const int row0 = q * H_DIM + cu * 8 + joff;

    // ---- one-time: W_hh fragment into registers (AGPR-backed array) ----
    // wreg[i][m] = W[row0+i][m*256 + lane*4 .. +3]   (coalesced 16B loads)
    v4f wreg[4][8];
#pragma unroll
    for (int i = 0; i < 4; i++) {
        const float* p = Whh + (size_t)(row0 + i) * H_DIM + lane * 4;
#pragma unroll
        for (int m = 0; m < 8; m++)
            wreg[i][m] = *(const v4f*)(p + m * 256);
    }
    // x-part: lane handles row (row0 + (lane>>4)), k-range (lane&15)*4 .. +4
    float xw[4];
    {
        const int xr = row0 + (lane >> 4);
        const float* p = Wih + (size_t)xr * I_DIM + (lane & 15) * 4;
#pragma unroll
        for (int m = 0; m < 4; m++) xw[m] = p[m];
    }
    // biases: every wave keeps them (elementwise phase is replicated per wave)
    float bias[4] = {0.f, 0.f, 0.f, 0.f};
    if (lane < 8) {
#pragma unroll
        for (int g = 0; g < 4; g++) {
            int r = g * H_DIM + cu * 8 + lane;
            bias[g] = bih[r] + bhh[r];
        }
    }
    float cstate = 0.0f;   // replicated in lanes 0..7 of every wave

    for (int t = 0; t < T_STEPS; t++) {
        const int slot_r = t & (NSLOT - 1);
        const int slot_w = (t + 1) & (NSLOT - 1);
        const int slot_z = (t + 2) & (NSLOT - 1);

        // hoist the independent x load above the spin
        float xv_own = (tid < I_DIM) ? x[(size_t)t * I_DIM + tid] : 0.0f;

        // ---- 1. poll h_t (data-as-flag) and stage into LDS ----
        // s_sleep(2) backoff on failed passes (round 6: FETCH -35%, dur -9%).
        {
            const unsigned int* Hr = Hbits + slot_r * H_DIM;
            unsigned int u0, u1, u2, u3;
            for (;;) {
                u0 = __hip_atomic_load(Hr + tid,             __ATOMIC_RELAXED, __HIP_MEMORY_SCOPE_AGENT);
                u1 = __hip_atomic_load(Hr + tid + 1 * NTHR,  __ATOMIC_RELAXED, __HIP_MEMORY_SCOPE_AGENT);
                u2 = __hip_atomic_load(Hr + tid + 2 * NTHR,  __ATOMIC_RELAXED, __HIP_MEMORY_SCOPE_AGENT);
                u3 = __hip_atomic_load(Hr + tid + 3 * NTHR,  __ATOMIC_RELAXED, __HIP_MEMORY_SCOPE_AGENT);
                bool miss = (u0 == NAN_BITS) | (u1 == NAN_BITS) |
                            (u2 == NAN_BITS) | (u3 == NAN_BITS);
                if (!miss) break;
                __builtin_amdgcn_s_sleep(2);
            }
            hbuf[tid]            = __uint_as_float(u0);
            hbuf[tid + 1 * NTHR] = __uint_as_float(u1);
            hbuf[tid + 2 * NTHR] = __uint_as_float(u2);
            hbuf[tid + 3 * NTHR] = __uint_as_float(u3);
            if (tid < I_DIM) xbuf[tid] = xv_own;
        }
        // reset own chunk 2 slots ahead (holds h_{t-2}, fully consumed, skew<=1).
        // Coalesced: 8 lanes of wave 0, one 32B transaction.
        if (w == 0 && lane < 8) {
            __hip_atomic_store(Hbits + slot_z * H_DIM + cu * 8 + lane, NAN_BITS,
                               __ATOMIC_RELAXED, __HIP_MEMORY_SCOPE_AGENT);
        }
        __syncthreads();

        // ---- 2. dot products: 4 rows per wave, 8 x (ds_read_b128 + packed FMA) ----
        v4f av0 = {0.f,0.f,0.f,0.f}, av1 = {0.f,0.f,0.f,0.f};
        v4f av2 = {0.f,0.f,0.f,0.f}, av3 = {0.f,0.f,0.f,0.f};
#pragma unroll
        for (int m = 0; m < 8; m++) {
            v4f hv = *(const v4f*)&hbuf[m * 256 + lane * 4];
            av0 += wreg[0][m] * hv;
            av1 += wreg[1][m] * hv;
            av2 += wreg[2][m] * hv;
            av3 += wreg[3][m] * hv;
        }
        float acc0 = av0[0] + av0[1] + av0[2] + av0[3];
        float acc1 = av1[0] + av1[1] + av1[2] + av1[3];
        float acc2 = av2[0] + av2[1] + av2[2] + av2[3];
        float acc3 = av3[0] + av3[1] + av3[2] + av3[3];
        {   // fold in W_ih * x_t
            float xp = 0.f;
            const int b = (lane & 15) * 4;
#pragma unroll
            for (int m = 0; m < 4; m++) xp += xw[m] * xbuf[b + m];
            const int sel = lane >> 4;
            acc0 += (sel == 0) ? xp : 0.0f;
            acc1 += (sel == 1) ? xp : 0.0f;
            acc2 += (sel == 2) ? xp : 0.0f;
            acc3 += (sel == 3) ? xp : 0.0f;
        }
#pragma unroll
        for (int off = 32; off; off >>= 1) {
            acc0 += __shfl_xor(acc0, off, 64);
            acc1 += __shfl_xor(acc1, off, 64);
            acc2 += __shfl_xor(acc2, off, 64);
            acc3 += __shfl_xor(acc3, off, 64);
        }
        if (lane == 0) {
            gbuf[q * 8 + joff + 0] = acc0;
            gbuf[q * 8 + joff + 1] = acc1;
            gbuf[q * 8 + joff + 2] = acc2;
            gbuf[q * 8 + joff + 3] = acc3;
        }
        __syncthreads();

        // ---- 3. elementwise cell update, replicated in every wave (lanes 0..7);
        //         wave 0 publishes — ONE coalesced 32B store = the ready flag ----
        if (lane < 8) {
            float gi = gbuf[0 * 8 + lane] + bias[0];
            float gf = gbuf[1 * 8 + lane] + bias[1];
            float gg = gbuf[2 * 8 + lane] + bias[2];
            float go = gbuf[3 * 8 + lane] + bias[3];
            float iv = sigmoid_f(gi);
            float fv = sigmoid_f(gf);
            float gv = tanh_fast(gg);
            float ov = sigmoid_f(go);
            cstate = fv * cstate + iv * gv;
            float hval = ov * tanh_fast(cstate);
            if (w == 0) {
                __hip_atomic_store(Hbits + slot_w * H_DIM + cu * 8 + lane,
                                   __float_as_uint(hval),
                                   __ATOMIC_RELAXED, __HIP_MEMORY_SCOPE_AGENT);
            }
        }
        // next iteration's poll phase touches only Hbits/hbuf/xbuf; gbuf reuse
        // is protected by the next iteration's first __syncthreads.
    }
}

// Final linear: out[o] = h_T . W_lin[o,:] + b_lin[o].  One wave per output.
// h_T lives in slot (T & 3) == 0.
__global__ void final_linear(const float* __restrict__ hT,
                             const float* __restrict__ Wlin,
                             const float* __restrict__ blin,
                             float* __restrict__ out)
{
    int gw   = (blockIdx.x * blockDim.x + threadIdx.x) >> 6;
    int lane = threadIdx.x & 63;
    if (gw < O_DIM) {
        const float* wp = Wlin + (size_t)gw * H_DIM;
        float s = 0.f;
        for (int k = lane; k < H_DIM; k += 64)
            s += wp[k] * hT[k];
#pragma unroll
        for (int off = 32; off; off >>= 1) s += __shfl_xor(s, off, 64);
        if (lane == 0) out[gw] = s + blin[gw];
    }
}

extern "C" void kernel_launch(void* const* d_in, const int* in_sizes, int n_in,
                              void* d_out, int out_size, void* d_ws, size_t ws_size,
                              hipStream_t stream)
{
    const float* x    = (const float*)d_in[0];
    const float* Wih  = (const float*)d_in[1];
    const float* Whh  = (const float*)d_in[2];
    const float* bih  = (const float*)d_in[3];
    const float* bhh  = (const float*)d_in[4];
    const float* Wlin = (const float*)d_in[5];
    const float* blin = (const float*)d_in[6];
    float* out = (float*)d_out;

    unsigned int* Hbits = (unsigned int*)d_ws;

    hipLaunchKernelGGL(init_ws_kernel, dim3((NSLOT * H_DIM + 255) / 256), dim3(256),
                       0, stream, Hbits);

    void* args[] = { (void*)&x, (void*)&Wih, (void*)&Whh, (void*)&bih, (void*)&bhh,
                     (void*)&Hbits };
    hipLaunchCooperativeKernel(reinterpret_cast<void*>(lstm_persistent),
                               dim3(NBLK), dim3(NTHR), args, 0, stream);

    // h_T is in slot (T_STEPS & 3) == 0
    hipLaunchKernelGGL(final_linear, dim3(32), dim3(256), 0, stream,
                       (const float*)Hbits, Wlin, blin, out);
}

// Round 9
// 19199.706 us; speedup vs baseline: 3.1416x; 1.1001x over previous
//
#include <hip/hip_runtime.h>
#include <math.h>

#define T_STEPS 8192
#define I_DIM   64
#define H_DIM   2048
#define O_DIM   128
#define NBLK    256     // one block per CU; each owns 8 h-indices (32 gate rows)
#define NTHR    512     // 8 waves
#define NSLOT   4       // h slot ring depth
#define NAN_BITS 0x7FC00000u

typedef float v4f __attribute__((ext_vector_type(4)));

// ws layout: float Hbuf[NSLOT][2048]
__device__ __forceinline__ float sigmoid_f(float x) {
    return 1.0f / (1.0f + __expf(-x));
}
__device__ __forceinline__ float tanh_fast(float x) {
    // 2*sigmoid(2x)-1; saturates correctly for |x| large
    return 2.0f / (1.0f + __expf(-2.0f * x)) - 1.0f;
}

// DPP-based wave64 sum — VALU pipe, NOT the LDS pipe (__shfl_xor = ds_bpermute
// burns ~1150 cy/step/CU of LDS throughput at 8 waves; DPP adds are VALU).
// CTRL must be an immediate -> template parameter (round-8 compile fix).
template <int CTRL>
__device__ __forceinline__ float dpp_add(float v) {
    int s = __builtin_amdgcn_update_dpp(0, __builtin_bit_cast(int, v),
                                        CTRL, 0xF, 0xF, true);
    return v + __builtin_bit_cast(float, s);
}
// After the sequence, lane 63 holds the full 64-lane sum.
__device__ __forceinline__ float wave_sum64_lane63(float v) {
    v = dpp_add<0x111>(v);  // row_shr:1
    v = dpp_add<0x112>(v);  // row_shr:2
    v = dpp_add<0x114>(v);  // row_shr:4
    v = dpp_add<0x118>(v);  // row_shr:8   -> lane15 of each row16 = row-partial
    v = dpp_add<0x142>(v);  // row_bcast:15 -> lane31 = sum(0..31), l63 = sum(32..63)
    v = dpp_add<0x143>(v);  // row_bcast:31 -> lane63 = sum(0..63)
    return v;
}

__global__ void init_ws_kernel(unsigned int* Hbits) {
    int tid = blockIdx.x * blockDim.x + threadIdx.x;
    if (tid < NSLOT * H_DIM) {
        // slot 0 = h_0 = 0.0f; slots 1..3 = NaN sentinel ("not ready")
        Hbits[tid] = (tid < H_DIM) ? 0u : NAN_BITS;
    }
}

// Persistent LSTM recurrence — round-7 fabric (proven 2.58 us/step) with the
// reduction moved from LDS pipe (shfl/ds_bpermute) to VALU pipe (DPP).
// One block per CU. Data-as-flag (NaN sentinel) h ring in LLC, agent-scope
// relaxed atomics only. Publish/reset are ONE coalesced 8-lane store from
// wave 0 (WRITE_SIZE signature 131 MB — do not scatter; scattering was the
// round-4/5 8x-write regression).
// Wave w: gate q = w>>1, joff = (w&1)*4; rows = q*2048 + cu*8 + joff + i
// Dot k-mapping: lane l covers k = m*256 + l*4 + j -> one ds_read_b128 per m.
__global__ __launch_bounds__(NTHR, 2) void lstm_persistent(
    const float* __restrict__ x,     // [T, 64]
    const float* __restrict__ Wih,   // [8192, 64]
    const float* __restrict__ Whh,   // [8192, 2048]
    const float* __restrict__ bih,   // [8192]
    const float* __restrict__ bhh,   // [8192]
    unsigned int* __restrict__ Hbits)// [NSLOT][2048] in ws (float bits)
{
    const int cu   = blockIdx.x;
    const int tid  = threadIdx.x;
    const int w    = tid >> 6;
    const int lane = tid & 63;

    __shared__ float hbuf[H_DIM];   // 8 KB, layout hbuf[k] = h[k]
    __shared__ float xbuf[I_DIM];
    __shared__ float gbuf[32];      // gbuf[g*8 + j] = pre-activation of gate g, h-sub j

    const int q    = w >> 1;
    const int joff = (w & 1) * 4;
    const int row0 = q * H_DIM + cu * 8 + joff;

    // ---- one-time: W_hh fragment into registers (unified VGPR/AGPR file) ----
    // wreg[i][m] = W[row0+i][m*256 + lane*4 .. +3]   (coalesced 16B loads)
    v4f wreg[4][8];
#pragma unroll
    for (int i = 0; i < 4; i++) {
        const float* p = Whh + (size_t)(row0 + i) * H_DIM + lane * 4;
#pragma unroll
        for (int m = 0; m < 8; m++)
            wreg[i][m] = *(const v4f*)(p + m * 256);
    }
    // x-part: lane handles row (row0 + (lane>>4)), k-range (lane&15)*4 .. +4
    float xw[4];
    {
        const int xr = row0 + (lane >> 4);
        const float* p = Wih + (size_t)xr * I_DIM + (lane & 15) * 4;
#pragma unroll
        for (int m = 0; m < 4; m++) xw[m] = p[m];
    }
    // biases: every wave keeps them (elementwise phase is replicated per wave)
    float bias[4] = {0.f, 0.f, 0.f, 0.f};
    if (lane < 8) {
#pragma unroll
        for (int g = 0; g < 4; g++) {
            int r = g * H_DIM + cu * 8 + lane;
            bias[g] = bih[r] + bhh[r];
        }
    }
    float cstate = 0.0f;   // replicated in lanes 0..7 of every wave

    for (int t = 0; t < T_STEPS; t++) {
        const int slot_r = t & (NSLOT - 1);
        const int slot_w = (t + 1) & (NSLOT - 1);
        const int slot_z = (t + 2) & (NSLOT - 1);

        // hoist the independent x load above the spin
        float xv_own = (tid < I_DIM) ? x[(size_t)t * I_DIM + tid] : 0.0f;

        // ---- 1. poll h_t (data-as-flag) and stage into LDS ----
        // s_sleep(2) backoff on failed passes (round 6: FETCH -35%, dur -9%).
        {
            const unsigned int* Hr = Hbits + slot_r * H_DIM;
            unsigned int u0, u1, u2, u3;
            for (;;) {
                u0 = __hip_atomic_load(Hr + tid,             __ATOMIC_RELAXED, __HIP_MEMORY_SCOPE_AGENT);
                u1 = __hip_atomic_load(Hr + tid + 1 * NTHR,  __ATOMIC_RELAXED, __HIP_MEMORY_SCOPE_AGENT);
                u2 = __hip_atomic_load(Hr + tid + 2 * NTHR,  __ATOMIC_RELAXED, __HIP_MEMORY_SCOPE_AGENT);
                u3 = __hip_atomic_load(Hr + tid + 3 * NTHR,  __ATOMIC_RELAXED, __HIP_MEMORY_SCOPE_AGENT);
                bool miss = (u0 == NAN_BITS) | (u1 == NAN_BITS) |
                            (u2 == NAN_BITS) | (u3 == NAN_BITS);
                if (!miss) break;
                __builtin_amdgcn_s_sleep(2);
            }
            hbuf[tid]            = __uint_as_float(u0);
            hbuf[tid + 1 * NTHR] = __uint_as_float(u1);
            hbuf[tid + 2 * NTHR] = __uint_as_float(u2);
            hbuf[tid + 3 * NTHR] = __uint_as_float(u3);
            if (tid < I_DIM) xbuf[tid] = xv_own;
        }
        // reset own chunk 2 slots ahead (holds h_{t-2}, fully consumed, skew<=1).
        // Coalesced: 8 lanes of wave 0, one 32B transaction.
        if (w == 0 && lane < 8) {
            __hip_atomic_store(Hbits + slot_z * H_DIM + cu * 8 + lane, NAN_BITS,
                               __ATOMIC_RELAXED, __HIP_MEMORY_SCOPE_AGENT);
        }
        __syncthreads();

        // ---- 2. dot products: 4 rows per wave, 8 x (ds_read_b128 + packed FMA) ----
        v4f av0 = {0.f,0.f,0.f,0.f}, av1 = {0.f,0.f,0.f,0.f};
        v4f av2 = {0.f,0.f,0.f,0.f}, av3 = {0.f,0.f,0.f,0.f};
#pragma unroll
        for (int m = 0; m < 8; m++) {
            v4f hv = *(const v4f*)&hbuf[m * 256 + lane * 4];
            av0 += wreg[0][m] * hv;
            av1 += wreg[1][m] * hv;
            av2 += wreg[2][m] * hv;
            av3 += wreg[3][m] * hv;
        }
        float acc0 = (av0[0] + av0[1]) + (av0[2] + av0[3]);
        float acc1 = (av1[0] + av1[1]) + (av1[2] + av1[3]);
        float acc2 = (av2[0] + av2[1]) + (av2[2] + av2[3]);
        float acc3 = (av3[0] + av3[1]) + (av3[2] + av3[3]);
        {   // fold in W_ih * x_t
            float xp = 0.f;
            const int b = (lane & 15) * 4;
#pragma unroll
            for (int m = 0; m < 4; m++) xp += xw[m] * xbuf[b + m];
            const int sel = lane >> 4;
            acc0 += (sel == 0) ? xp : 0.0f;
            acc1 += (sel == 1) ? xp : 0.0f;
            acc2 += (sel == 2) ? xp : 0.0f;
            acc3 += (sel == 3) ? xp : 0.0f;
        }
        // ---- 3. DPP reduction (VALU pipe); totals land in lane 63 ----
        acc0 = wave_sum64_lane63(acc0);
        acc1 = wave_sum64_lane63(acc1);
        acc2 = wave_sum64_lane63(acc2);
        acc3 = wave_sum64_lane63(acc3);
        if (lane == 63) {
            gbuf[q * 8 + joff + 0] = acc0;
            gbuf[q * 8 + joff + 1] = acc1;
            gbuf[q * 8 + joff + 2] = acc2;
            gbuf[q * 8 + joff + 3] = acc3;
        }
        __syncthreads();

        // ---- 4. elementwise cell update, replicated in every wave (lanes 0..7);
        //         wave 0 publishes — ONE coalesced 32B store = the ready flag ----
        if (lane < 8) {
            float gi = gbuf[0 * 8 + lane] + bias[0];
            float gf = gbuf[1 * 8 + lane] + bias[1];
            float gg = gbuf[2 * 8 + lane] + bias[2];
            float go = gbuf[3 * 8 + lane] + bias[3];
            float iv = sigmoid_f(gi);
            float fv = sigmoid_f(gf);
            float gv = tanh_fast(gg);
            float ov = sigmoid_f(go);
            cstate = fv * cstate + iv * gv;
            float hval = ov * tanh_fast(cstate);
            if (w == 0) {
                __hip_atomic_store(Hbits + slot_w * H_DIM + cu * 8 + lane,
                                   __float_as_uint(hval),
                                   __ATOMIC_RELAXED, __HIP_MEMORY_SCOPE_AGENT);
            }
        }
        // next iteration's poll phase touches only Hbits/hbuf/xbuf; gbuf reuse
        // is protected by the next iteration's first __syncthreads.
    }
}

// Final linear: out[o] = h_T . W_lin[o,:] + b_lin[o].  One wave per output.
// h_T lives in slot (T & 3) == 0.
__global__ void final_linear(const float* __restrict__ hT,
                             const float* __restrict__ Wlin,
                             const float* __restrict__ blin,
                             float* __restrict__ out)
{
    int gw   = (blockIdx.x * blockDim.x + threadIdx.x) >> 6;
    int lane = threadIdx.x & 63;
    if (gw < O_DIM) {
        const float* wp = Wlin + (size_t)gw * H_DIM;
        float s = 0.f;
        for (int k = lane; k < H_DIM; k += 64)
            s += wp[k] * hT[k];
#pragma unroll
        for (int off = 32; off; off >>= 1) s += __shfl_xor(s, off, 64);
        if (lane == 0) out[gw] = s + blin[gw];
    }
}

extern "C" void kernel_launch(void* const* d_in, const int* in_sizes, int n_in,
                              void* d_out, int out_size, void* d_ws, size_t ws_size,
                              hipStream_t stream)
{
    const float* x    = (const float*)d_in[0];
    const float* Wih  = (const float*)d_in[1];
    const float* Whh  = (const float*)d_in[2];
    const float* bih  = (const float*)d_in[3];
    const float* bhh  = (const float*)d_in[4];
    const float* Wlin = (const float*)d_in[5];
    const float* blin = (const float*)d_in[6];
    float* out = (float*)d_out;

    unsigned int* Hbits = (unsigned int*)d_ws;

    hipLaunchKernelGGL(init_ws_kernel, dim3((NSLOT * H_DIM + 255) / 256), dim3(256),
                       0, stream, Hbits);

    void* args[] = { (void*)&x, (void*)&Wih, (void*)&Whh, (void*)&bih, (void*)&bhh,
                     (void*)&Hbits };
    (void)hipLaunchCooperativeKernel(reinterpret_cast<void*>(lstm_persistent),
                                     dim3(NBLK), dim3(NTHR), args, 0, stream);

    // h_T is in slot (T_STEPS & 3) == 0
    hipLaunchKernelGGL(final_linear, dim3(32), dim3(256), 0, stream,
                       (const float*)Hbits, Wlin, blin, out);
}